// Round 8
// baseline (221.324 us; speedup 1.0000x reference)
//
#include <hip/hip_runtime.h>
#include <cstdint>
#include <cstddef>

typedef unsigned short u16;
typedef short short8 __attribute__((ext_vector_type(8)));
typedef float floatx4 __attribute__((ext_vector_type(4)));

#define DEVINL __device__ __forceinline__

static constexpr int BSZ = 8, SEQL = 4096, H = 512, P = 256;
static constexpr int M = BSZ * SEQL;       // 32768 rows
static constexpr int KD = 512;             // K for both GEMMs
static constexpr int ND = 512;             // N for both GEMMs
static constexpr int CHUNK = 128;          // = gemm0 row-tile -> carry fused into gemm0
static constexpr int NCH = SEQL / CHUNK;   // 32 chunks

DEVINL u16 f2bf(float f) {
  union { float f; unsigned u; } v; v.f = f;
  unsigned r = (v.u + 0x7fffu + ((v.u >> 16) & 1u)) >> 16;
  return (u16)r;
}
DEVINL float bf2f(u16 h) {
  union { unsigned u; float f; } v; v.u = ((unsigned)h) << 16; return v.f;
}

// async global->LDS, 16B per lane. LDS dest must be wave-uniform base + lane*16.
DEVINL void gload_lds16(const void* g, void* l) {
  __builtin_amdgcn_global_load_lds(
      (const __attribute__((address_space(1))) unsigned*)g,
      (__attribute__((address_space(3))) unsigned*)l, 16, 0, 0);
}

// lam[p] = exp(Lambda[p] * step[p]), computed inline
DEVINL float2 lam_of(int p, const float* __restrict__ Lre, const float* __restrict__ Lim,
                     const float* __restrict__ lstep) {
  float lr = Lre[p], li = Lim[p];
  float st = expf(lstep[p]);
  float mag = expf(lr * st);
  float ang = li * st;
  return make_float2(mag * cosf(ang), mag * sinf(ang));
}

// ---------- prep: bt1 (f*B_tilde components) and bt2 (+-2C), one kernel ----------
__global__ void prep_kernel(const float2* __restrict__ Bin, const float* __restrict__ Cin,
                            const float* __restrict__ Lre, const float* __restrict__ Lim,
                            const float* __restrict__ lstep,
                            u16* __restrict__ bt1, u16* __restrict__ bt2) {
  int bid = blockIdx.x;
  if (bid < 512) {
    int idx = bid * 256 + threadIdx.x;   // over P*H
    int p = idx / H, h = idx % H;
    float lr = Lre[p], li = Lim[p];
    float st = expf(lstep[p]);
    float mag = expf(lr * st);
    float ang = li * st;
    float cr = mag * cosf(ang), ci = mag * sinf(ang);
    float a = cr - 1.0f, b = ci;
    float den = lr * lr + li * li;
    float fr = (a * lr + b * li) / den;
    float fi = (b * lr - a * li) / den;
    float2 bv = Bin[(size_t)p * H + h];
    float br = fr * bv.x - fi * bv.y;
    float bi = fr * bv.y + fi * bv.x;
    bt1[(size_t)(2 * p) * H + h]     = f2bf(br);
    bt1[(size_t)(2 * p + 1) * H + h] = f2bf(bi);
  } else {
    int idx = (bid - 512) * 256 + threadIdx.x;   // over H*P*2
    float c = Cin[idx];
    float v = (idx & 1) ? -2.0f * c : 2.0f * c;
    bt2[idx] = f2bf(v);
  }
}

// ---------- GEMM0: Bu[M][N] = u[M][K](f32, cvt on the fly) * bt1[N][K]^T ----------
// R6-proven 2-stage dbuf + f32-A XOR source swizzle. NEW: carry epilogue —
// block (bm,bn) owns chunk c=bm&31 of batch b=bm>>5 for p in [bn*64, bn*64+64);
// after C-store + full-drain barrier, wave 0 reads the block's own (L2-hot)
// C-tile back and runs the 128-step recurrence -> carry. scan_carry eliminated.
__global__ __launch_bounds__(256, 3) void gemm0(const float* __restrict__ Af32,
                                                const u16* __restrict__ Bt,
                                                u16* __restrict__ outBf,
                                                const float* __restrict__ Lre,
                                                const float* __restrict__ Lim,
                                                const float* __restrict__ lstep,
                                                float2* __restrict__ carry) {
  __shared__ float Asf[2][128 * 32];  // 2 x 16 KB
  __shared__ u16   Bs[2][128 * 32];   // 2 x 8 KB
  const int tid = threadIdx.x;
  const int bm = blockIdx.x, bn = blockIdx.y;
  const int wave = tid >> 6, lane = tid & 63;
  const int quad = lane >> 4, l16 = lane & 15;
  const int wm = (wave & 1) << 6, wn = (wave >> 1) << 6;

  floatx4 acc[4][4] = {};

  const float* Ab = Af32 + (size_t)bm * 128 * KD;
  const u16*   Bb = Bt + (size_t)bn * 128 * KD;
  const int srowA = tid >> 3;
  const int scolA = (((tid & 7) ^ ((tid >> 3) & 7)) << 2);   // f32 offset, swizzled source
  const int srowB = tid >> 2;
  const int scolB = (tid & 3) << 3;

#define STAGE0(buf, kofs)                                                                     \
  do {                                                                                        \
    gload_lds16(Ab + (size_t)srowA * KD + (kofs) + scolA,        &Asf[buf][tid * 4]);         \
    gload_lds16(Ab + (size_t)(srowA + 32) * KD + (kofs) + scolA, &Asf[buf][1024 + tid * 4]);  \
    gload_lds16(Ab + (size_t)(srowA + 64) * KD + (kofs) + scolA, &Asf[buf][2048 + tid * 4]);  \
    gload_lds16(Ab + (size_t)(srowA + 96) * KD + (kofs) + scolA, &Asf[buf][3072 + tid * 4]);  \
    gload_lds16(Bb + (size_t)srowB * KD + (kofs) + scolB,        &Bs[buf][tid * 8]);          \
    gload_lds16(Bb + (size_t)(srowB + 64) * KD + (kofs) + scolB, &Bs[buf][2048 + tid * 8]);   \
  } while (0)

  // prologue
  STAGE0(0, 0);
  asm volatile("s_waitcnt vmcnt(0)" ::: "memory");
  __builtin_amdgcn_sched_barrier(0);
  __builtin_amdgcn_s_barrier();

  // read-side swizzled chunk index: rows r = wm + t*16 + l16 -> r&7 == l16&7
  const int c0 = ((quad << 1) ^ (l16 & 7));
  const int c1 = c0 ^ 1;

  int cur = 0;
  for (int k0 = 0; k0 < KD; k0 += 32) {
    if (k0 + 32 < KD) STAGE0(cur ^ 1, k0 + 32);

    short8 af[4], bfr[4];
#pragma unroll
    for (int t = 0; t < 4; t++) {
      const float* rowp = &Asf[cur][(wm + t * 16 + l16) * 32];
      float4 a0 = *(const float4*)(rowp + c0 * 4);
      float4 a1 = *(const float4*)(rowp + c1 * 4);
      af[t][0] = (short)f2bf(a0.x); af[t][1] = (short)f2bf(a0.y);
      af[t][2] = (short)f2bf(a0.z); af[t][3] = (short)f2bf(a0.w);
      af[t][4] = (short)f2bf(a1.x); af[t][5] = (short)f2bf(a1.y);
      af[t][6] = (short)f2bf(a1.z); af[t][7] = (short)f2bf(a1.w);
    }
#pragma unroll
    for (int t = 0; t < 4; t++)
      bfr[t] = *(const short8*)&Bs[cur][(wn + t * 16 + l16) * 32 + quad * 8];

    asm volatile("s_waitcnt lgkmcnt(0)" ::: "memory");
    __builtin_amdgcn_sched_barrier(0);

    __builtin_amdgcn_s_setprio(1);
#pragma unroll
    for (int tm = 0; tm < 4; tm++)
#pragma unroll
      for (int tn = 0; tn < 4; tn++)
        acc[tm][tn] = __builtin_amdgcn_mfma_f32_16x16x32_bf16(af[tm], bfr[tn], acc[tm][tn], 0, 0, 0);
    __builtin_amdgcn_s_setprio(0);

    asm volatile("s_waitcnt vmcnt(0)" ::: "memory");
    __builtin_amdgcn_sched_barrier(0);
    __builtin_amdgcn_s_barrier();
    cur ^= 1;
  }
#undef STAGE0

  // epilogue: C/D layout col = lane&15, row = quad*4 + reg  [m89-verified]
  const int row_base = bm * 128 + wm + quad * 4;
  const int col_base = bn * 128 + wn + l16;
#pragma unroll
  for (int tm = 0; tm < 4; tm++)
#pragma unroll
    for (int tn = 0; tn < 4; tn++) {
      int n = col_base + tn * 16;
#pragma unroll
      for (int r = 0; r < 4; r++) {
        int m = row_base + tm * 16 + r;
        outBf[(size_t)m * ND + n] = f2bf(acc[tm][tn][r]);
      }
    }

  // ---- carry epilogue: recurrence over this block's own freshly-written tile ----
  __syncthreads();   // compiler emits vmcnt(0) drain: all tile stores complete & visible
  if (tid < 64) {
    const int lp = tid;
    const int p = bn * 64 + lp;
    const int cix = bm & 31, b = bm >> 5;
    float2 lm = lam_of(p, Lre, Lim, lstep);
    const u16* tb = outBf + (size_t)(bm * 128) * ND + bn * 128 + 2 * lp;
    float xr = 0.f, xi = 0.f;
    for (int l0 = 0; l0 < 128; l0 += 8) {
      unsigned w[8];
#pragma unroll
      for (int t = 0; t < 8; t++)
        w[t] = *(const unsigned*)(tb + (size_t)(l0 + t) * ND);
#pragma unroll
      for (int t = 0; t < 8; t++) {
        float br = bf2f((u16)(w[t] & 0xffffu));
        float bi = bf2f((u16)(w[t] >> 16));
        float nr = lm.x * xr - lm.y * xi + br;
        float ni = lm.x * xi + lm.y * xr + bi;
        xr = nr; xi = ni;
      }
    }
    carry[((size_t)b * NCH + cix) * P + p] = make_float2(xr, xi);
  }
}

// ---------- GEMM1: ys = xs[M][K] * bt2[N][K]^T + D[n]*u, gelu -> f32 ----------
// R6-proven 2-stage dbuf structure, unchanged.
__global__ __launch_bounds__(256, 4) void gemm1(const u16* __restrict__ A,
                                                const u16* __restrict__ Bt,
                                                float* __restrict__ outF,
                                                const float* __restrict__ Dv,
                                                const float* __restrict__ U32) {
  __shared__ u16 As[2][128 * 32];   // 2 x 8 KB
  __shared__ u16 Bs[2][128 * 32];   // 2 x 8 KB
  const int tid = threadIdx.x;
  const int bm = blockIdx.x, bn = blockIdx.y;
  const int wave = tid >> 6, lane = tid & 63;
  const int quad = lane >> 4, l16 = lane & 15;
  const int wm = (wave & 1) << 6, wn = (wave >> 1) << 6;

  floatx4 acc[4][4] = {};

  const u16* Ab = A + (size_t)bm * 128 * KD;
  const u16* Bb = Bt + (size_t)bn * 128 * KD;
  const int srow = tid >> 2;
  const int scol = (tid & 3) << 3;

#define STAGE1(buf, kofs)                                                                  \
  do {                                                                                     \
    gload_lds16(Ab + (size_t)srow * KD + (kofs) + scol,        &As[buf][tid * 8]);         \
    gload_lds16(Ab + (size_t)(srow + 64) * KD + (kofs) + scol, &As[buf][2048 + tid * 8]);  \
    gload_lds16(Bb + (size_t)srow * KD + (kofs) + scol,        &Bs[buf][tid * 8]);         \
    gload_lds16(Bb + (size_t)(srow + 64) * KD + (kofs) + scol, &Bs[buf][2048 + tid * 8]);  \
  } while (0)

  STAGE1(0, 0);
  asm volatile("s_waitcnt vmcnt(0)" ::: "memory");
  __builtin_amdgcn_sched_barrier(0);
  __builtin_amdgcn_s_barrier();

  int cur = 0;
  for (int k0 = 0; k0 < KD; k0 += 32) {
    if (k0 + 32 < KD) STAGE1(cur ^ 1, k0 + 32);

    short8 af[4], bfr[4];
#pragma unroll
    for (int t = 0; t < 4; t++)
      af[t] = *(const short8*)&As[cur][(wm + t * 16 + l16) * 32 + quad * 8];
#pragma unroll
    for (int t = 0; t < 4; t++)
      bfr[t] = *(const short8*)&Bs[cur][(wn + t * 16 + l16) * 32 + quad * 8];

    asm volatile("s_waitcnt lgkmcnt(0)" ::: "memory");
    __builtin_amdgcn_sched_barrier(0);

    __builtin_amdgcn_s_setprio(1);
#pragma unroll
    for (int tm = 0; tm < 4; tm++)
#pragma unroll
      for (int tn = 0; tn < 4; tn++)
        acc[tm][tn] = __builtin_amdgcn_mfma_f32_16x16x32_bf16(af[tm], bfr[tn], acc[tm][tn], 0, 0, 0);
    __builtin_amdgcn_s_setprio(0);

    asm volatile("s_waitcnt vmcnt(0)" ::: "memory");
    __builtin_amdgcn_sched_barrier(0);
    __builtin_amdgcn_s_barrier();
    cur ^= 1;
  }
#undef STAGE1

  const int row_base = bm * 128 + wm + quad * 4;
  const int col_base = bn * 128 + wn + l16;
  float dv[4];
#pragma unroll
  for (int tn = 0; tn < 4; tn++) dv[tn] = Dv[col_base + tn * 16];
#pragma unroll
  for (int tm = 0; tm < 4; tm++)
#pragma unroll
    for (int tn = 0; tn < 4; tn++) {
      int n = col_base + tn * 16;
#pragma unroll
      for (int r = 0; r < 4; r++) {
        int m = row_base + tm * 16 + r;
        float ys = acc[tm][tn][r] + dv[tn] * U32[(size_t)m * ND + n];
        // gelu(ys) = ys * sigmoid(1.59577*(ys + 0.044715*ys^3)); exp via HW exp2
        float zz = ys + 0.044715f * (ys * ys * ys);
        float e = __builtin_amdgcn_exp2f(-2.3022082f * zz);
        outF[(size_t)m * ND + n] = ys * __builtin_amdgcn_rcpf(1.0f + e);
      }
    }
}

// ---------- scan apply: batched prefix over <=31 carries, then 128-row apply ----------
// CHUNK=128 (matches gemm0's fused carry granularity). 8-deep independent load
// batches keep L2/HBM latency off the recurrence's critical path.
__global__ __launch_bounds__(256) void scan_apply(u16* __restrict__ Bu,
                                                  const float* __restrict__ Lre,
                                                  const float* __restrict__ Lim,
                                                  const float* __restrict__ lstep,
                                                  const float2* __restrict__ carry) {
  int p = threadIdx.x;
  int c = blockIdx.x;       // 0..31
  int b = blockIdx.y;
  float2 lm = lam_of(p, Lre, Lim, lstep);
  // A = lm^CHUNK (CHUNK = 128 = 2^7)
  float ar = lm.x, ai = lm.y;
#pragma unroll
  for (int i = 0; i < 7; i++) { float nr = ar * ar - ai * ai, ni = 2.f * ar * ai; ar = nr; ai = ni; }
  // prefix_c: p <- A*p + carry_j over j in [0,c)
  float pr = 0.f, pi = 0.f;
  const float2* cb_base = carry + (size_t)b * NCH * P + p;
  for (int j0 = 0; j0 < c; j0 += 16) {
    float2 cb[16];
#pragma unroll
    for (int t = 0; t < 16; t++) {
      int j = j0 + t;
      int jc = j < c ? j : c - 1;          // clamp address (loop entered => c >= 1)
      cb[t] = cb_base[(size_t)jc * P];
    }
#pragma unroll
    for (int t = 0; t < 16; t++) {
      bool real = (j0 + t) < c;
      float mr = real ? ar : 1.0f;
      float mi = real ? ai : 0.0f;
      float cx = real ? cb[t].x : 0.0f;
      float cy = real ? cb[t].y : 0.0f;
      float nr = mr * pr - mi * pi + cx;
      float ni = mr * pi + mi * pr + cy;
      pr = nr; pi = ni;
    }
  }
  // apply over the 128-row chunk, 8-deep load batches, write xs in place
  float xr = pr, xi = pi;
  u16* base = Bu + ((size_t)b * SEQL + (size_t)c * CHUNK) * 512 + 2 * p;
  for (int l0 = 0; l0 < CHUNK; l0 += 8) {
    unsigned w[8];
#pragma unroll
    for (int t = 0; t < 8; t++)
      w[t] = *(const unsigned*)(base + (size_t)(l0 + t) * 512);
#pragma unroll
    for (int t = 0; t < 8; t++) {
      float br = bf2f((u16)(w[t] & 0xffffu));
      float bi = bf2f((u16)(w[t] >> 16));
      float nr = lm.x * xr - lm.y * xi + br;
      float ni = lm.x * xi + lm.y * xr + bi;
      xr = nr; xi = ni;
      *(unsigned*)(base + (size_t)(l0 + t) * 512) = (unsigned)f2bf(nr) | ((unsigned)f2bf(ni) << 16);
    }
  }
}

extern "C" void kernel_launch(void* const* d_in, const int* in_sizes, int n_in,
                              void* d_out, int out_size, void* d_ws, size_t ws_size,
                              hipStream_t stream) {
  const float* u      = (const float*)d_in[0];   // (8,4096,512)
  const float* Lre    = (const float*)d_in[1];   // (256,)
  const float* Lim    = (const float*)d_in[2];   // (256,)
  const float* Bin    = (const float*)d_in[3];   // (256,512,2)
  const float* Cin    = (const float*)d_in[4];   // (512,256,2)
  const float* Dv     = (const float*)d_in[5];   // (512,)
  const float* lstep  = (const float*)d_in[6];   // (256,1)
  float* out          = (float*)d_out;           // (8,4096,512) f32

  char* ws = (char*)d_ws;
  u16*    bt1    = (u16*)   (ws + 0);                 // 512 KB
  u16*    bt2    = (u16*)   (ws + 524288);            // 512 KB
  u16*    Bu     = (u16*)   (ws + 1048576);           //  32 MB (becomes xs)
  float2* carry  = (float2*)(ws + 34603008);          // 512 KB

  prep_kernel<<<1536, 256, 0, stream>>>((const float2*)Bin, Cin, Lre, Lim, lstep, bt1, bt2);

  gemm0<<<dim3(M / 128, ND / 128), 256, 0, stream>>>(u, bt1, Bu, Lre, Lim, lstep, carry);

  scan_apply<<<dim3(NCH, BSZ), 256, 0, stream>>>(Bu, Lre, Lim, lstep, carry);

  gemm1<<<dim3(M / 128, ND / 128), 256, 0, stream>>>(Bu, bt2, out, Dv, u);
}